// Round 7
// baseline (103.836 us; speedup 1.0000x reference)
//
#include <hip/hip_runtime.h>

// Fused MLPKAN. Block = 512 threads (8 waves), TB = 32 batches, grid = 512
// (2 blocks/CU -> 4 waves/SIMD). Wave = (iq = i-quarter, bh = batch-half).
//   Layer0: lane = o; Layer1: lane = ig*16+o1, ig reduced via shfl_xor.
// Round-7 change: pack pairs of BATCHES into v2f (not the H=2 hidden dim).
// Weights become whole-pair broadcasts {w,w}, built ONCE per i (hoisted out
// of the 8-pair j-loop) -> inner body is pure v_pk_fma_f32 / v_max_f32:
// 8 instr per batch-subnet vs ~12 for H-packing (which needed per-j
// cross-half moves and had no v_pk_max_f32 anyway).

typedef float v2f __attribute__((ext_vector_type(2)));

#define BATCH 16384
#define TB    32

__global__ __launch_bounds__(512, 4) void kan_fused(
    const float* __restrict__ x,
    const float* __restrict__ A1, const float* __restrict__ a1,
    const float* __restrict__ A2, const float* __restrict__ a2,
    const float* __restrict__ A3, const float* __restrict__ a3,
    const float* __restrict__ B1, const float* __restrict__ c1,
    const float* __restrict__ B2, const float* __restrict__ c2,
    const float* __restrict__ B3, const float* __restrict__ c3,
    float* __restrict__ out)
{
    __shared__ float xs[64][36];        // x transposed: xs[i][b] (rows 144B, 16B-aligned)
    __shared__ float hp[4][TB][64];     // layer0 partials per i-quarter
    __shared__ float ht[64][36];        // h transposed: ht[i][b]
    __shared__ float op[4][TB][16];     // layer1 partials per i-quarter

    const int t    = threadIdx.x;
    const int lane = t & 63;
    const int wave = t >> 6;            // 0..7
    const int iq   = wave & 3;          // i-quarter: [16*iq, 16*iq+16)
    const int bh   = wave >> 2;         // batch-half: [16*bh, 16*bh+16)
    const int bB0  = blockIdx.x * TB;

    // ---- stage x transposed: 2048 floats, 512 thr x float4 (one-time) ----
    {
        const int k = t * 4;
        const float4 v = *(const float4*)(x + (long)bB0 * 64 + k);
        const int b = k >> 6, i = k & 63;
        xs[i][b] = v.x; xs[i + 1][b] = v.y; xs[i + 2][b] = v.z; xs[i + 3][b] = v.w;
    }
    __syncthreads();

    const v2f zz = {0.f, 0.f};
    const int boff = 16 * bh;

    // ================= layer 0: 64 -> 64 =================
    {
        const int o  = lane;
        const int i0 = 16 * iq;

        auto ldw = [&](int i, v2f& w1, v2f& d1, float4& w2, v2f& d2, v2f& w3, float& b3v) {
            const int n = (i << 6) + o;
            w1  = *(const v2f*)(A1 + 2 * n);
            d1  = *(const v2f*)(a1 + 2 * n);
            w2  = *(const float4*)(A2 + 4 * n);
            d2  = *(const v2f*)(a2 + 2 * n);
            w3  = *(const v2f*)(A3 + 2 * n);
            b3v = a3[n];
        };

        v2f acc[8];
#pragma unroll
        for (int j = 0; j < 8; ++j) acc[j] = zz;
        float bsum = 0.f;

        v2f w1, d1, d2, w3; float4 w2; float b3v;
        ldw(i0, w1, d1, w2, d2, w3, b3v);

#pragma unroll 1
        for (int ii = 0; ii < 16; ++ii) {
            const int i = i0 + ii;
            v2f nw1, nd1, nd2, nw3; float4 nw2; float nb3;
            ldw(i0 + ((ii + 1) & 15), nw1, nd1, nw2, nd2, nw3, nb3);  // in flight

            // hoisted whole-pair broadcasts (once per i, amortized over 16 b)
            const v2f W1X = {w1.x, w1.x}, W1Y = {w1.y, w1.y};
            const v2f D1X = {d1.x, d1.x}, D1Y = {d1.y, d1.y};
            const v2f W2X = {w2.x, w2.x}, W2Y = {w2.y, w2.y};
            const v2f W2Z = {w2.z, w2.z}, W2W = {w2.w, w2.w};
            const v2f D2X = {d2.x, d2.x}, D2Y = {d2.y, d2.y};
            const v2f W3X = {w3.x, w3.x}, W3Y = {w3.y, w3.y};

            const float4 xv0 = *(const float4*)&xs[i][boff];          // ds b128
            const float4 xv1 = *(const float4*)&xs[i][boff + 4];
            const float4 xv2 = *(const float4*)&xs[i][boff + 8];
            const float4 xv3 = *(const float4*)&xs[i][boff + 12];
            const float4 xq[4] = {xv0, xv1, xv2, xv3};
            const v2f* xp = (const v2f*)xq;

            bsum += b3v;
#pragma unroll
            for (int jp = 0; jp < 8; ++jp) {                          // 2 batches/iter
                v2f m0 = __builtin_elementwise_fma(xp[jp], W1X, D1X);
                v2f m1 = __builtin_elementwise_fma(xp[jp], W1Y, D1Y);
                m0 = __builtin_elementwise_max(m0, zz);
                m1 = __builtin_elementwise_max(m1, zz);
                v2f t0 = __builtin_elementwise_fma(W2Y, m1, D2X);
                t0 = __builtin_elementwise_fma(W2X, m0, t0);
                v2f t1 = __builtin_elementwise_fma(W2W, m1, D2Y);
                t1 = __builtin_elementwise_fma(W2Z, m0, t1);
                t0 = __builtin_elementwise_max(t0, zz);
                t1 = __builtin_elementwise_max(t1, zz);
                acc[jp] = __builtin_elementwise_fma(W3X, t0, acc[jp]);
                acc[jp] = __builtin_elementwise_fma(W3Y, t1, acc[jp]);
            }
            w1 = nw1; d1 = nd1; w2 = nw2; d2 = nd2; w3 = nw3; b3v = nb3;
        }
#pragma unroll
        for (int jp = 0; jp < 8; ++jp) {
            hp[iq][boff + 2 * jp][o]     = acc[jp].x + bsum;
            hp[iq][boff + 2 * jp + 1][o] = acc[jp].y + bsum;
        }
    }
    __syncthreads();

    // ---- combine i-quarters + transpose: ht[i][b] = sum_q hp[q][b][i] ----
    for (int k = t; k < TB * 64; k += 512) {
        const int b = k >> 6, i = k & 63;
        ht[i][b] = hp[0][b][i] + hp[1][b][i] + hp[2][b][i] + hp[3][b][i];
    }
    __syncthreads();

    // ================= layer 1: 64 -> 16 =================
    {
        const int o1 = lane & 15;
        const int ig = lane >> 4;          // 4 i-subgroups of 4
        const int i0 = 16 * iq + 4 * ig;

        auto ldw = [&](int i, v2f& w1, v2f& d1, float4& w2, v2f& d2, v2f& w3, float& b3v) {
            const int n = (i << 4) + o1;
            w1  = *(const v2f*)(B1 + 2 * n);
            d1  = *(const v2f*)(c1 + 2 * n);
            w2  = *(const float4*)(B2 + 4 * n);
            d2  = *(const v2f*)(c2 + 2 * n);
            w3  = *(const v2f*)(B3 + 2 * n);
            b3v = c3[n];
        };

        v2f acc[8];
#pragma unroll
        for (int j = 0; j < 8; ++j) acc[j] = zz;
        float bsum = 0.f;

        v2f w1, d1, d2, w3; float4 w2; float b3v;
        ldw(i0, w1, d1, w2, d2, w3, b3v);

#pragma unroll 1
        for (int ii = 0; ii < 4; ++ii) {
            const int i = i0 + ii;
            v2f nw1, nd1, nd2, nw3; float4 nw2; float nb3;
            ldw(i0 + ((ii + 1) & 3), nw1, nd1, nw2, nd2, nw3, nb3);

            const v2f W1X = {w1.x, w1.x}, W1Y = {w1.y, w1.y};
            const v2f D1X = {d1.x, d1.x}, D1Y = {d1.y, d1.y};
            const v2f W2X = {w2.x, w2.x}, W2Y = {w2.y, w2.y};
            const v2f W2Z = {w2.z, w2.z}, W2W = {w2.w, w2.w};
            const v2f D2X = {d2.x, d2.x}, D2Y = {d2.y, d2.y};
            const v2f W3X = {w3.x, w3.x}, W3Y = {w3.y, w3.y};

            const float4 hv0 = *(const float4*)&ht[i][boff];
            const float4 hv1 = *(const float4*)&ht[i][boff + 4];
            const float4 hv2 = *(const float4*)&ht[i][boff + 8];
            const float4 hv3 = *(const float4*)&ht[i][boff + 12];
            const float4 hq[4] = {hv0, hv1, hv2, hv3};
            const v2f* hpair = (const v2f*)hq;

            bsum += b3v;
#pragma unroll
            for (int jp = 0; jp < 8; ++jp) {
                v2f m0 = __builtin_elementwise_fma(hpair[jp], W1X, D1X);
                v2f m1 = __builtin_elementwise_fma(hpair[jp], W1Y, D1Y);
                m0 = __builtin_elementwise_max(m0, zz);
                m1 = __builtin_elementwise_max(m1, zz);
                v2f t0 = __builtin_elementwise_fma(W2Y, m1, D2X);
                t0 = __builtin_elementwise_fma(W2X, m0, t0);
                v2f t1 = __builtin_elementwise_fma(W2W, m1, D2Y);
                t1 = __builtin_elementwise_fma(W2Z, m0, t1);
                t0 = __builtin_elementwise_max(t0, zz);
                t1 = __builtin_elementwise_max(t1, zz);
                acc[jp] = __builtin_elementwise_fma(W3X, t0, acc[jp]);
                acc[jp] = __builtin_elementwise_fma(W3Y, t1, acc[jp]);
            }
            w1 = nw1; d1 = nd1; w2 = nw2; d2 = nd2; w3 = nw3; b3v = nb3;
        }

        // reduce over ig (lanes 16 apart), write per-iq partial
#pragma unroll
        for (int jp = 0; jp < 8; ++jp) {
#pragma unroll
            for (int h = 0; h < 2; ++h) {
                float v = ((h == 0) ? acc[jp].x : acc[jp].y) + bsum;
                v += __shfl_xor(v, 16, 64);
                v += __shfl_xor(v, 32, 64);
                if (ig == 0) op[iq][boff + 2 * jp + h][o1] = v;
            }
        }
    }
    __syncthreads();

    // ---- store: out = sum_q op[q], 512 floats, float4 coalesced ----
    if (t < 128) {
        const int f = t * 4;
        const float4 p0 = *(const float4*)(&op[0][0][0] + f);
        const float4 p1 = *(const float4*)(&op[1][0][0] + f);
        const float4 p2 = *(const float4*)(&op[2][0][0] + f);
        const float4 p3 = *(const float4*)(&op[3][0][0] + f);
        float4 r;
        r.x = p0.x + p1.x + p2.x + p3.x;
        r.y = p0.y + p1.y + p2.y + p3.y;
        r.z = p0.z + p1.z + p2.z + p3.z;
        r.w = p0.w + p1.w + p2.w + p3.w;
        *(float4*)(out + (long)bB0 * 16 + f) = r;
    }
}

extern "C" void kernel_launch(void* const* d_in, const int* in_sizes, int n_in,
                              void* d_out, int out_size, void* d_ws, size_t ws_size,
                              hipStream_t stream) {
    const float* x     = (const float*)d_in[0];
    const float* l0_W1 = (const float*)d_in[1];
    const float* l0_b1 = (const float*)d_in[2];
    const float* l0_W2 = (const float*)d_in[3];
    const float* l0_b2 = (const float*)d_in[4];
    const float* l0_W3 = (const float*)d_in[5];
    const float* l0_b3 = (const float*)d_in[6];
    const float* l1_W1 = (const float*)d_in[7];
    const float* l1_b1 = (const float*)d_in[8];
    const float* l1_W2 = (const float*)d_in[9];
    const float* l1_b2 = (const float*)d_in[10];
    const float* l1_W3 = (const float*)d_in[11];
    const float* l1_b3 = (const float*)d_in[12];

    float* outp = (float*)d_out;

    dim3 blk(512);
    dim3 grid(BATCH / TB);   // 512 blocks, 2 per CU
    hipLaunchKernelGGL(kan_fused, grid, blk, 0, stream,
                       x,
                       l0_W1, l0_b1, l0_W2, l0_b2, l0_W3, l0_b3,
                       l1_W1, l1_b1, l1_W2, l1_b2, l1_W3, l1_b3,
                       outp);
}